// Round 2
// 413.901 us; speedup vs baseline: 1.0291x; 1.0291x over previous
//
#include <hip/hip_runtime.h>

// LIF scan over trailing time axis T=16.
// X: [4194304 pixels][16 timesteps] fp32, T contiguous.
//
// R1 lesson: thread-per-pixel direct loads have 64 B lane stride ->
// uncoalesced (64 lines/instr) -> 1.23 TB/s. Fix: coalesced float4
// global access + LDS transpose to pixel-private order and back.
//
// R2: wave-local transpose (each wave's 64 pixels x 4 quarters never
// cross the wave) -> replace 3 block-wide __syncthreads() with
// wave-private LDS regions + s_waitcnt lgkmcnt(0). Nontemporal global
// streams (zero reuse). R2b: use clang ext_vector float4 — the
// nontemporal builtins reject HIP_vector_type pointers.
//
// LDS layout per wave: f4 w_lds[quarter*65 + pixel]; pad 65 gives
// bank-quad = (quarter + pixel) % 8 -> 8 lanes per bank-quad in every
// phase = structural minimum for b128 (1024 B / 128 B-per-clk).

#define LIF_DECAY  0.5f
#define LIF_THRESH 1.0f

typedef float f4 __attribute__((ext_vector_type(4)));

// One LIF step on one float, in place. v holds x_t on entry, spike on exit.
#define LIF_STEP(v)                                        \
    {                                                      \
        m = m * LIF_DECAY + (v);                           \
        float sp = (m >= LIF_THRESH) ? 1.0f : 0.0f;        \
        (v) = sp;                                          \
        m = (sp != 0.0f) ? 0.0f : m;                       \
    }

__global__ __launch_bounds__(256) void lif_kernel(const f4* __restrict__ X4,
                                                  f4* __restrict__ O4) {
    // 256 threads = 4 waves; each wave owns 64 pixels = 256 float4.
    __shared__ f4 lds[4][4 * 65];

    const int tid = threadIdx.x;
    const int wv  = tid >> 6;        // wave id within block
    const int l   = tid & 63;        // lane
    const int q   = l & 3;           // quarter owned during coalesced phases
    const int p   = l >> 2;          // pixel-local base for coalesced phases

    f4* __restrict__ w_lds = &lds[wv][0];
    const size_t wbase = (size_t)blockIdx.x * 1024 + (size_t)wv * 256;

    // ---- Phase 1: coalesced nontemporal loads (4 x 1 KiB per wave),
    //      transpose into wave-private LDS ----
    f4 v0 = __builtin_nontemporal_load(&X4[wbase +   0 + l]);
    f4 v1 = __builtin_nontemporal_load(&X4[wbase +  64 + l]);
    f4 v2 = __builtin_nontemporal_load(&X4[wbase + 128 + l]);
    f4 v3 = __builtin_nontemporal_load(&X4[wbase + 192 + l]);
    // float4 idx m = 64k + l: pixel_local = 16k + (l>>2), quarter = l&3
    w_lds[q * 65 + ( 0 + p)] = v0;
    w_lds[q * 65 + (16 + p)] = v1;
    w_lds[q * 65 + (32 + p)] = v2;
    w_lds[q * 65 + (48 + p)] = v3;

    // Cross-lane RAW within this wave only: wait for OUR writes to land.
    // No __syncthreads — other waves are in disjoint LDS regions.
    asm volatile("s_waitcnt lgkmcnt(0)" ::: "memory");

    // ---- Phase 2: pixel-private read (lane l owns pixel l), register scan ----
    f4 f0 = w_lds[0 * 65 + l];
    f4 f1 = w_lds[1 * 65 + l];
    f4 f2 = w_lds[2 * 65 + l];
    f4 f3 = w_lds[3 * 65 + l];

    float m = 0.0f;
    LIF_STEP(f0.x) LIF_STEP(f0.y) LIF_STEP(f0.z) LIF_STEP(f0.w)
    LIF_STEP(f1.x) LIF_STEP(f1.y) LIF_STEP(f1.z) LIF_STEP(f1.w)
    LIF_STEP(f2.x) LIF_STEP(f2.y) LIF_STEP(f2.z) LIF_STEP(f2.w)
    LIF_STEP(f3.x) LIF_STEP(f3.y) LIF_STEP(f3.z) LIF_STEP(f3.w)

    // ---- Phase 3: spikes -> the SAME lane-private slots we just read.
    //      (Each lane writes only addresses it alone read: no cross-lane
    //      WAR hazard, so no sync needed between phases 2 and 3.) ----
    w_lds[0 * 65 + l] = f0;
    w_lds[1 * 65 + l] = f1;
    w_lds[2 * 65 + l] = f2;
    w_lds[3 * 65 + l] = f3;

    // Cross-lane RAW (phase 4 reads other lanes' spikes): wave-local wait.
    asm volatile("s_waitcnt lgkmcnt(0)" ::: "memory");

    // ---- Phase 4: coalesced nontemporal stores ----
    __builtin_nontemporal_store(w_lds[q * 65 + ( 0 + p)], &O4[wbase +   0 + l]);
    __builtin_nontemporal_store(w_lds[q * 65 + (16 + p)], &O4[wbase +  64 + l]);
    __builtin_nontemporal_store(w_lds[q * 65 + (32 + p)], &O4[wbase + 128 + l]);
    __builtin_nontemporal_store(w_lds[q * 65 + (48 + p)], &O4[wbase + 192 + l]);
}

extern "C" void kernel_launch(void* const* d_in, const int* in_sizes, int n_in,
                              void* d_out, int out_size, void* d_ws, size_t ws_size,
                              hipStream_t stream) {
    (void)n_in; (void)d_ws; (void)ws_size; (void)out_size;
    const f4* X4 = (const f4*)d_in[0];
    f4* O4 = (f4*)d_out;

    // 67,108,864 floats = 16,777,216 float4 = 16384 blocks x 1024 float4.
    int n_f4 = in_sizes[0] / 4;
    int grid = n_f4 / 1024;          // exact: 16384
    lif_kernel<<<grid, 256, 0, stream>>>(X4, O4);
}